// Round 8
// baseline (220.500 us; speedup 1.0000x reference)
//
#include <hip/hip_runtime.h>
#include <hip/hip_fp16.h>
#include <cstring>

// Problem constants (fixed by reference setup_inputs)
constexpr int N_NODES = 50000;
constexpr int N_EDGES = 800000;
constexpr int DIM     = 128;
constexpr int DIM4    = DIM / 4;          // 32 float4 (or uint2-fp16) cols per row
constexpr float BN_EPS = 1e-5f;

constexpr int EMPTY = 0x7F7F7F7F;         // > any edge index; min-stable sentinel

// Two-stage select: 16 node chunks x 16 edge chunks, 1024-thread scan blocks.
constexpr int NC = 16;
constexpr int EC = 16;
constexpr int NODES_PER_NC = N_NODES / NC;      // 3125 (50 KB LDS table)
constexpr int EDGES_PER_EC = N_EDGES / EC;      // 50000
constexpr int E4_PER_EC    = EDGES_PER_EC / 4;  // 12500 int4 loads per chunk
constexpr int SEL_THREADS  = 1024;

constexpr int NBUCKETS = 16;              // stats buckets (16 -> cheap inline reduce)
constexpr int ZERO_WORDS = 2 * NBUCKETS * 256;   // both layers' stats, zeroed in stageB

// Stage B: 2 threads per node, 128 nodes per 256-thread block -> 391 blocks;
// extra blocks convert x0 -> fp16 shadow (6250) and blank projections (2).
constexpr int NB_MERGE = (N_NODES + 127) / 128;  // 391
constexpr int NCVT = N_NODES * DIM4 / 256;       // 6250 convert blocks (exact)

// Conv: 128-thread blocks, 4 nodes per THREAD (16/block) -> 16 gather
// instructions in flight per wave (2x the old 8): attacks the measured
// latency/concurrency bound (R7: halving gather bytes changed nothing).
constexpr int CONV_THREADS = 128;
constexpr int CONV_NPB     = 16;
constexpr int CONV_GRID    = N_NODES / CONV_NPB;   // 3125 exact, no guard

// ---------------- helpers ----------------
__device__ inline float4 f4min(float4 a, float4 b) {
    return make_float4(fminf(a.x,b.x), fminf(a.y,b.y), fminf(a.z,b.z), fminf(a.w,b.w));
}
__device__ inline float4 f4max(float4 a, float4 b) {
    return make_float4(fmaxf(a.x,b.x), fmaxf(a.y,b.y), fmaxf(a.z,b.z), fmaxf(a.w,b.w));
}
__device__ inline float4 f4add(float4 a, float4 b) {
    return make_float4(a.x+b.x, a.y+b.y, a.z+b.z, a.w+b.w);
}
__device__ inline float4 f4fma(float s, float4 v, float4 acc) {   // acc + s*v
    return make_float4(fmaf(s,v.x,acc.x), fmaf(s,v.y,acc.y), fmaf(s,v.z,acc.z), fmaf(s,v.w,acc.w));
}
__device__ inline __half2 u2h2(unsigned u) { __half2 h; memcpy(&h, &u, 4); return h; }
__device__ inline unsigned h22u(__half2 h) { unsigned u; memcpy(&u, &h, 4); return u; }
__device__ inline float4 q2f4(uint2 q) {                 // fp16x4 -> fp32x4
    const float2 lo = __half22float2(u2h2(q.x));
    const float2 hi = __half22float2(u2h2(q.y));
    return make_float4(lo.x, lo.y, hi.x, hi.y);
}

// ---------------------------------------------------------------------------
// Select stage A: block (nc, ec) scans edge chunk ec with 1024 threads,
// inserts edges whose dst lies in node chunk nc into an LDS top-4 table
// (cascaded LDS atomicMin = concurrent sorted insert), then streams the
// table to tables[ec][node] with plain coalesced stores (one writer/cell).
// ---------------------------------------------------------------------------
__global__ __launch_bounds__(SEL_THREADS)
void select_stageA_kernel(const int* __restrict__ dst,
                          int* __restrict__ tables) {
    __shared__ int slot[NODES_PER_NC * 4];    // 50 KB
    const int nc = blockIdx.x & (NC - 1);
    const int ec = blockIdx.x >> 4;
    const int t  = threadIdx.x;

    for (int i = t; i < NODES_PER_NC * 4; i += SEL_THREADS) slot[i] = EMPTY;
    __syncthreads();

    const int r0 = nc * NODES_PER_NC;
    const int4* __restrict__ dst4 = (const int4*)dst;
    const int base4 = ec * E4_PER_EC;
    for (int i = t; i < E4_PER_EC; i += SEL_THREADS) {
        const int4 d = dst4[base4 + i];
        const int ebase = 4 * (base4 + i);
        #define TRY_INS(comp, off) {                                        \
            unsigned n_ = (unsigned)((comp) - r0);                          \
            if (n_ < (unsigned)NODES_PER_NC) {                              \
                int cur_ = ebase + (off);                                   \
                _Pragma("unroll")                                           \
                for (int j_ = 0; j_ < 4; ++j_) {                            \
                    int old_ = atomicMin(&slot[4 * n_ + j_], cur_);         \
                    if (old_ == EMPTY) break;                               \
                    cur_ = max(cur_, old_);                                 \
                } } }
        TRY_INS(d.x, 0); TRY_INS(d.y, 1); TRY_INS(d.z, 2); TRY_INS(d.w, 3);
        #undef TRY_INS
    }
    __syncthreads();

    int4* __restrict__ out = (int4*)tables + (size_t)ec * N_NODES + r0;
    const int4* __restrict__ sl4 = (const int4*)slot;
    for (int n = t; n < NODES_PER_NC; n += SEL_THREADS) out[n] = sl4[n];
}

// ---------------------------------------------------------------------------
// Select stage B: blocks [0, NB_MERGE): 2 threads/node branchless 16-list
// merge (bitonic half-cleaner), map through src, zero stats. Blocks
// NB_MERGE/NB_MERGE+1: blank projections. Blocks >= NB_MERGE+2: convert
// x0 -> fp16 shadow xh (gathers read 256B rows instead of 512B).
// ---------------------------------------------------------------------------
__global__ __launch_bounds__(256)
void select_stageB_kernel(const int* __restrict__ tables,
                          const int* __restrict__ src,
                          int4* __restrict__ srcs4,
                          float* __restrict__ stats_part,   // zeroed here
                          const float* __restrict__ x0,
                          uint2* __restrict__ xh4,          // fp16 shadow out
                          const float* __restrict__ W0, const float* __restrict__ b0,
                          const float* __restrict__ bl0,
                          const float* __restrict__ W1, const float* __restrict__ b1,
                          const float* __restrict__ bl1,
                          float* __restrict__ bp) {
    const int t = threadIdx.x;

    if (blockIdx.x >= NB_MERGE + 2) {     // x0 -> fp16 convert blocks
        const int i = (blockIdx.x - NB_MERGE - 2) * 256 + t;   // float4 idx, exact
        const float4 v = ((const float4*)x0)[i];
        uint2 u;
        u.x = h22u(__floats2half2_rn(v.x, v.y));
        u.y = h22u(__floats2half2_rn(v.z, v.w));
        xh4[i] = u;
        return;
    }

    if (blockIdx.x >= NB_MERGE) {         // blank-projection blocks
        if (t < DIM) {
            int l = blockIdx.x - NB_MERGE;
            const float* W  = l ? W1  : W0;
            const float* b  = l ? b1  : b0;
            const float* bl = l ? bl1 : bl0;
            float s = 0.f;
            #pragma unroll 8
            for (int j = 0; j < DIM; ++j) s += W[t * DIM + j] * bl[j];
            bp[l * DIM + t] = s + b[t];
        }
        return;
    }

    const int gid = blockIdx.x * 256 + t;
    if (gid < ZERO_WORDS) stats_part[gid] = 0.f;   // fold the stats memset

    const int vloc = t & 127;
    const int half = t >> 7;
    int v = blockIdx.x * 128 + vloc;
    const bool valid = (v < N_NODES);
    if (!valid) v = N_NODES - 1;          // clamp: loads stay in-bounds

    // 8 unconditional, independent chunk-list loads (coalesced per half)
    int4 c[8];
    #pragma unroll
    for (int j = 0; j < 8; ++j)
        c[j] = ((const int4*)tables)[(size_t)(half * 8 + j) * N_NODES + v];

    int a0 = c[0].x, a1 = c[0].y, a2 = c[0].z, a3 = c[0].w;
    #define MERGE4(cx, cy, cz, cw) {                                 \
        int m0 = min(a0, (cw)), m1 = min(a1, (cz));                  \
        int m2 = min(a2, (cy)), m3 = min(a3, (cx));                  \
        int u_;                                                      \
        u_ = min(m0, m2); m2 = max(m0, m2); m0 = u_;                 \
        u_ = min(m1, m3); m3 = max(m1, m3); m1 = u_;                 \
        u_ = min(m0, m1); m1 = max(m0, m1); m0 = u_;                 \
        u_ = min(m2, m3); m3 = max(m2, m3); m2 = u_;                 \
        a0 = m0; a1 = m1; a2 = m2; a3 = m3; }
    #pragma unroll
    for (int j = 1; j < 8; ++j) MERGE4(c[j].x, c[j].y, c[j].z, c[j].w);

    __shared__ int4 xbuf[128];
    if (half) xbuf[vloc] = make_int4(a0, a1, a2, a3);
    __syncthreads();
    if (!half) {
        const int4 o = xbuf[vloc];
        MERGE4(o.x, o.y, o.z, o.w);
        int4 r;
        r.x = (a0 < N_EDGES) ? src[a0] : -1;
        r.y = (a1 < N_EDGES) ? src[a1] : -1;
        r.z = (a2 < N_EDGES) ? src[a2] : -1;
        r.w = (a3 < N_EDGES) ? src[a3] : -1;
        if (valid) srcs4[v] = r;
    }
    #undef MERGE4
}

// ---------------------------------------------------------------------------
// Fused sort-conv + BN statistics. 128 threads, 4 nodes per thread: all 4
// srcs4 loads then all 20 row loads (16 gathers + 4 own) issued fully
// unrolled BEFORE any compute -> 2x outstanding requests per wave vs the
// 2-node version (attacks the R7-measured latency bound). Gathers read the
// fp16 shadow (256B rows); fp32 sort + dot; h stays fp32.
// ---------------------------------------------------------------------------
__global__ __launch_bounds__(CONV_THREADS)
void conv_stats_kernel(const uint2* __restrict__ xh4,     // fp16 shadow of xin
                       const int4* __restrict__ srcs4,    // per-node 4 gather rows
                       const float* __restrict__ bp,      // 128 floats (this layer)
                       const float* __restrict__ cw,
                       const float* __restrict__ cb,
                       const float* __restrict__ a,
                       float* __restrict__ h,
                       float* __restrict__ stats_part) {  // [NBUCKETS][256]
    const int t    = threadIdx.x;
    const int d4   = t & (DIM4 - 1);
    const int nsub = t >> 5;                  // 0..3

    float4* __restrict__ h4 = (float4*)h;

    const float aa = a[0];
    const float c0 = cw[0], c1 = cw[1], c2 = cw[2], c3 = cw[3];
    const float cbv = cb[0];
    const float4 bpv = ((const float4*)bp)[d4];

    const int vb = blockIdx.x * CONV_NPB + nsub;   // node k at vb + 4*k

    // ---- issue ALL loads first (static indexing, fully unrolled) ----
    int4 sv[4];
    #pragma unroll
    for (int k = 0; k < 4; ++k) sv[k] = srcs4[vb + 4 * k];

    uint2 q[4][4], xq[4];
    #pragma unroll
    for (int k = 0; k < 4; ++k) {
        q[k][0] = xh4[(size_t)max(sv[k].x, 0) * DIM4 + d4];
        q[k][1] = xh4[(size_t)max(sv[k].y, 0) * DIM4 + d4];
        q[k][2] = xh4[(size_t)max(sv[k].z, 0) * DIM4 + d4];
        q[k][3] = xh4[(size_t)max(sv[k].w, 0) * DIM4 + d4];
        xq[k]   = xh4[(size_t)(vb + 4 * k) * DIM4 + d4];
    }

    float4 s  = make_float4(0.f, 0.f, 0.f, 0.f);
    float4 s2 = make_float4(0.f, 0.f, 0.f, 0.f);

    #define CSWAP4(p, q) { float4 lo = f4min(p, q); float4 hi = f4max(p, q); p = lo; q = hi; }
    #pragma unroll
    for (int k = 0; k < 4; ++k) {
        float4 m0 = (sv[k].x >= 0) ? q2f4(q[k][0]) : bpv;
        float4 m1 = (sv[k].y >= 0) ? q2f4(q[k][1]) : bpv;
        float4 m2 = (sv[k].z >= 0) ? q2f4(q[k][2]) : bpv;
        float4 m3 = (sv[k].w >= 0) ? q2f4(q[k][3]) : bpv;
        CSWAP4(m0, m1); CSWAP4(m2, m3); CSWAP4(m0, m2); CSWAP4(m1, m3); CSWAP4(m1, m2);
        float4 hv = make_float4(cbv, cbv, cbv, cbv);
        hv = f4fma(c0, m0, hv);
        hv = f4fma(c1, m1, hv);
        hv = f4fma(c2, m2, hv);
        hv = f4fma(c3, m3, hv);
        hv = f4fma(aa, q2f4(xq[k]), hv);
        h4[(size_t)(vb + 4 * k) * DIM4 + d4] = hv;
        s  = f4add(s, hv);
        s2 = f4add(s2, make_float4(hv.x*hv.x, hv.y*hv.y, hv.z*hv.z, hv.w*hv.w));
    }
    #undef CSWAP4

    // intra-wave: lane i += lane i+32 (same d4 column, different node)
    s.x  += __shfl_down(s.x, 32);  s.y  += __shfl_down(s.y, 32);
    s.z  += __shfl_down(s.z, 32);  s.w  += __shfl_down(s.w, 32);
    s2.x += __shfl_down(s2.x, 32); s2.y += __shfl_down(s2.y, 32);
    s2.z += __shfl_down(s2.z, 32); s2.w += __shfl_down(s2.w, 32);

    __shared__ float4 ls[2][32];
    __shared__ float4 ls2[2][32];
    const int wave = t >> 6;                  // 0..1
    const int lane = t & 63;
    if (lane < 32) { ls[wave][lane] = s; ls2[wave][lane] = s2; }
    __syncthreads();
    if (t < 32) {
        float* bucket = stats_part + (size_t)(blockIdx.x & (NBUCKETS - 1)) * 256;
        float4 fs  = f4add(ls[0][t],  ls[1][t]);
        float4 fs2 = f4add(ls2[0][t], ls2[1][t]);
        atomicAdd(&bucket[4*t + 0], fs.x);
        atomicAdd(&bucket[4*t + 1], fs.y);
        atomicAdd(&bucket[4*t + 2], fs.z);
        atomicAdd(&bucket[4*t + 3], fs.w);
        atomicAdd(&bucket[DIM + 4*t + 0], fs2.x);
        atomicAdd(&bucket[DIM + 4*t + 1], fs2.y);
        atomicAdd(&bucket[DIM + 4*t + 2], fs2.z);
        atomicAdd(&bucket[DIM + 4*t + 3], fs2.w);
    }
}

// ---------------------------------------------------------------------------
// BN apply with inline bucket finalize; optionally emits the fp16 shadow of
// xout (layer 0) for the next layer's gathers.
// ---------------------------------------------------------------------------
__global__ __launch_bounds__(256)
void bn_apply_kernel(const float* __restrict__ xin,
                     const float* __restrict__ h,
                     const float* __restrict__ stats_part,  // [NBUCKETS][256]
                     const float* __restrict__ g,
                     const float* __restrict__ be,
                     float* __restrict__ xout,
                     uint2* __restrict__ xh4,               // fp16 shadow out
                     const int write_shadow) {
    __shared__ float acc[256];
    const int t = threadIdx.x;

    float ssum = 0.f;
    #pragma unroll
    for (int k = 0; k < NBUCKETS; ++k) ssum += stats_part[k * 256 + t];
    acc[t] = ssum;
    __syncthreads();
    if (t < 128) {
        constexpr float invN = 1.0f / (float)N_NODES;
        float mu = acc[t] * invN;
        float iv = rsqrtf(acc[128 + t] * invN - mu * mu + BN_EPS);
        acc[t]       = mu;
        acc[128 + t] = iv;
    }
    __syncthreads();

    const int idx = blockIdx.x * 256 + t;   // float4 index; grid exact
    const int d4 = idx & (DIM4 - 1);

    const float4 mu4 = make_float4(acc[4*d4+0], acc[4*d4+1], acc[4*d4+2], acc[4*d4+3]);
    const float4 iv4 = make_float4(acc[128+4*d4+0], acc[128+4*d4+1],
                                   acc[128+4*d4+2], acc[128+4*d4+3]);
    const float4 hv = ((const float4*)h)[idx];
    const float4 xv = ((const float4*)xin)[idx];
    const float4 gv = ((const float4*)g)[d4];
    const float4 bv = ((const float4*)be)[d4];

    float4 o;
    o.x = xv.x + (hv.x - mu4.x) * iv4.x * gv.x + bv.x;
    o.y = xv.y + (hv.y - mu4.y) * iv4.y * gv.y + bv.y;
    o.z = xv.z + (hv.z - mu4.z) * iv4.z * gv.z + bv.z;
    o.w = xv.w + (hv.w - mu4.w) * iv4.w * gv.w + bv.w;
    ((float4*)xout)[idx] = o;
    if (write_shadow) {
        uint2 u;
        u.x = h22u(__floats2half2_rn(o.x, o.y));
        u.y = h22u(__floats2half2_rn(o.z, o.w));
        xh4[idx] = u;
    }
}

extern "C" void kernel_launch(void* const* d_in, const int* in_sizes, int n_in,
                              void* d_out, int out_size, void* d_ws, size_t ws_size,
                              hipStream_t stream) {
    const float* x0  = (const float*)d_in[0];
    const int*   ei  = (const int*)d_in[1];
    const int*   src = ei;               // edge_index[0]
    const int*   dst = ei + N_EDGES;     // edge_index[1]

    const float* W[2]; const float* b[2]; const float* cw[2]; const float* cb[2];
    const float* a[2]; const float* g[2]; const float* be[2]; const float* blank[2];
    for (int i = 0; i < 2; ++i) {
        int o = 2 + 8 * i;
        W[i]     = (const float*)d_in[o + 0];
        b[i]     = (const float*)d_in[o + 1];
        cw[i]    = (const float*)d_in[o + 2];
        cb[i]    = (const float*)d_in[o + 3];
        a[i]     = (const float*)d_in[o + 4];
        g[i]     = (const float*)d_in[o + 5];
        be[i]    = (const float*)d_in[o + 6];
        blank[i] = (const float*)d_in[o + 7];
    }

    // Workspace layout (re-poisoned 0xAA each call — everything used is
    // written before read). tables (stage A output, 12.8 MB) aliases the h
    // region: tables is dead before conv_stats writes h. xh (fp16 shadow,
    // 12.8 MB) is separate — written by stageB (x0) then bn_apply l=0.
    char* ws = (char*)d_ws;
    int*   srcs       = (int*)ws;                                 // 4N ints
    float* h          = (float*)(srcs + 4 * N_NODES);             // 25.6 MB
    int*   tables     = (int*)h;                                  // alias: 12.8 MB
    uint2* xh4        = (uint2*)(h + (size_t)N_NODES * DIM);      // 12.8 MB fp16 shadow
    float* stats_part = (float*)(xh4 + (size_t)N_NODES * DIM4);   // 2*16*256 floats
    float* bp         = stats_part + ZERO_WORDS;                  // 256 floats

    float* xout = (float*)d_out;

    // ---- two-stage selection + x0 fp16 shadow ----
    select_stageA_kernel<<<NC * EC, SEL_THREADS, 0, stream>>>(dst, tables);
    select_stageB_kernel<<<NB_MERGE + 2 + NCVT, 256, 0, stream>>>(
        tables, src, (int4*)srcs, stats_part, x0, xh4,
        W[0], b[0], blank[0], W[1], b[1], blank[1], bp);

    // ---- two layers: conv+stats (4-node ILP), BN apply w/ finalize ----
    for (int l = 0; l < 2; ++l) {
        const float* xin = (l == 0) ? x0 : xout;
        float* sp = stats_part + (size_t)l * NBUCKETS * 256;
        conv_stats_kernel<<<CONV_GRID, CONV_THREADS, 0, stream>>>(
            xh4, (const int4*)srcs, bp + l * DIM, cw[l], cb[l], a[l], h, sp);
        bn_apply_kernel<<<(N_NODES * DIM4) / 256, 256, 0, stream>>>(
            xin, h, sp, g[l], be[l], xout, xh4, (l == 0) ? 1 : 0);
    }
}

// Round 9
// 216.134 us; speedup vs baseline: 1.0202x; 1.0202x over previous
//
#include <hip/hip_runtime.h>

// Problem constants (fixed by reference setup_inputs)
constexpr int N_NODES = 50000;
constexpr int N_EDGES = 800000;
constexpr int DIM     = 128;
constexpr int DIM4    = DIM / 4;          // 32 float4 columns
constexpr float BN_EPS = 1e-5f;

constexpr int EMPTY = 0x7F7F7F7F;         // > any edge index; min-stable sentinel

// Partition-based selection: 256 bins of 196 nodes. Each edge examined ONCE
// (vs 16x in the old chunked stageA) and no merge stage: one block per bin
// builds the FINAL top-4 per node in a 3 KB LDS table.
constexpr int NBINS   = 256;
constexpr int NPB_BIN = 196;              // 256*196 = 50176 >= 50000
constexpr int P1_BLOCKS  = 200;
constexpr int I4_PER_P1  = 1000;          // 200*1000 int4 = 200000 = E/4

constexpr int NBUCKETS = 16;              // stats buckets (cheap inline reduce)
constexpr int ZERO_WORDS = 2 * NBUCKETS * 256;   // zeroed in P1

// Conv: proven R4 structure. 256 threads = 8 nodes x 32 f4-cols, 2 iters.
constexpr int NODES_PER_ITER  = 8;
constexpr int NODES_PER_BLOCK = 16;
constexpr int CONV_GRID = N_NODES / NODES_PER_BLOCK;   // 3125 exact, no guard

// ---------------- float4 helpers ----------------
__device__ inline float4 f4min(float4 a, float4 b) {
    return make_float4(fminf(a.x,b.x), fminf(a.y,b.y), fminf(a.z,b.z), fminf(a.w,b.w));
}
__device__ inline float4 f4max(float4 a, float4 b) {
    return make_float4(fmaxf(a.x,b.x), fmaxf(a.y,b.y), fmaxf(a.z,b.z), fmaxf(a.w,b.w));
}
__device__ inline float4 f4add(float4 a, float4 b) {
    return make_float4(a.x+b.x, a.y+b.y, a.z+b.z, a.w+b.w);
}
__device__ inline float4 f4fma(float s, float4 v, float4 acc) {   // acc + s*v
    return make_float4(fmaf(s,v.x,acc.x), fmaf(s,v.y,acc.y), fmaf(s,v.z,acc.z), fmaf(s,v.w,acc.w));
}

// ---------------------------------------------------------------------------
// P1: per-block 256-bin LDS histogram of dst -> hist[block][bin].
// Also zeroes stats_part (fold the memset).
// ---------------------------------------------------------------------------
__global__ __launch_bounds__(256)
void part_count_kernel(const int* __restrict__ dst,
                       int* __restrict__ hist,
                       float* __restrict__ stats_part) {
    __shared__ int hl[NBINS];
    const int t = threadIdx.x;
    hl[t] = 0;

    const int gid = blockIdx.x * 256 + t;
    if (gid < ZERO_WORDS) stats_part[gid] = 0.f;
    __syncthreads();

    const int4* __restrict__ dst4 = (const int4*)dst;
    const int base = blockIdx.x * I4_PER_P1;
    for (int i = t; i < I4_PER_P1; i += 256) {
        const int4 d = dst4[base + i];
        atomicAdd(&hl[(unsigned)d.x / NPB_BIN], 1);
        atomicAdd(&hl[(unsigned)d.y / NPB_BIN], 1);
        atomicAdd(&hl[(unsigned)d.z / NPB_BIN], 1);
        atomicAdd(&hl[(unsigned)d.w / NPB_BIN], 1);
    }
    __syncthreads();
    hist[blockIdx.x * NBINS + t] = hl[t];
}

// ---------------------------------------------------------------------------
// P2: one block. Thread b: column-sum hist[*][b] -> bin totals; LDS
// exclusive scan over bins -> bin_base; second pass writes per-block
// scatter offsets offsets[k][b] = bin_base[b] + prefix_k.
// ---------------------------------------------------------------------------
__global__ __launch_bounds__(256)
void part_offsets_kernel(const int* __restrict__ hist,
                         int* __restrict__ offsets,
                         int* __restrict__ bin_base) {
    __shared__ int tot[NBINS];
    const int b = threadIdx.x;

    int total = 0;
    for (int k = 0; k < P1_BLOCKS; ++k) total += hist[k * NBINS + b];
    tot[b] = total;
    __syncthreads();

    // Hillis-Steele inclusive scan
    for (int s = 1; s < NBINS; s <<= 1) {
        int v = (b >= s) ? tot[b - s] : 0;
        __syncthreads();
        tot[b] += v;
        __syncthreads();
    }
    const int base = tot[b] - total;      // exclusive
    bin_base[b] = base;
    if (b == NBINS - 1) bin_base[NBINS] = N_EDGES;

    int running = base;
    for (int k = 0; k < P1_BLOCKS; ++k) {
        offsets[k * NBINS + b] = running;
        running += hist[k * NBINS + b];
    }
}

// ---------------------------------------------------------------------------
// P3: scatter edges into their bins as int2(dst, edge_id). Per-block LDS
// copy of its offsets; LDS atomicAdd gives unique positions.
// ---------------------------------------------------------------------------
__global__ __launch_bounds__(256)
void part_scatter_kernel(const int* __restrict__ dst,
                         const int* __restrict__ offsets,
                         int2* __restrict__ bins2) {
    __shared__ int off[NBINS];
    const int t = threadIdx.x;
    off[t] = offsets[blockIdx.x * NBINS + t];
    __syncthreads();

    const int4* __restrict__ dst4 = (const int4*)dst;
    const int base = blockIdx.x * I4_PER_P1;
    for (int i = t; i < I4_PER_P1; i += 256) {
        const int4 d = dst4[base + i];
        const int ebase = 4 * (base + i);
        #define SCAT(comp, o) {                                    \
            const int b_ = (unsigned)(comp) / NPB_BIN;             \
            const int p_ = atomicAdd(&off[b_], 1);                 \
            bins2[p_] = make_int2((comp), ebase + (o)); }
        SCAT(d.x, 0); SCAT(d.y, 1); SCAT(d.z, 2); SCAT(d.w, 3);
        #undef SCAT
    }
}

// ---------------------------------------------------------------------------
// P4: blocks [0,NBINS): single-pass EXACT select. Block b scans bin b
// (~3125 edges) inserting edge ids into a 196x4 LDS top-4 table (cascaded
// LDS atomicMin — proven concurrent sorted insert), then maps through src
// and writes final srcs4. No merge stage. Blocks NBINS/NBINS+1: blank
// projections bp[l] = W_l @ blank_l + b_l.
// ---------------------------------------------------------------------------
__global__ __launch_bounds__(256)
void select_kernel(const int2* __restrict__ bins2,
                   const int* __restrict__ bin_base,
                   const int* __restrict__ src,
                   int4* __restrict__ srcs4,
                   const float* __restrict__ W0, const float* __restrict__ b0,
                   const float* __restrict__ bl0,
                   const float* __restrict__ W1, const float* __restrict__ b1,
                   const float* __restrict__ bl1,
                   float* __restrict__ bp) {
    const int t = threadIdx.x;

    if (blockIdx.x >= NBINS) {            // blank-projection blocks
        if (t < DIM) {
            int l = blockIdx.x - NBINS;
            const float* W  = l ? W1  : W0;
            const float* b  = l ? b1  : b0;
            const float* bl = l ? bl1 : bl0;
            float s = 0.f;
            #pragma unroll 8
            for (int j = 0; j < DIM; ++j) s += W[t * DIM + j] * bl[j];
            bp[l * DIM + t] = s + b[t];
        }
        return;
    }

    __shared__ int slot[NPB_BIN * 4];     // 3.1 KB
    for (int i = t; i < NPB_BIN * 4; i += 256) slot[i] = EMPTY;
    __syncthreads();

    const int nb    = blockIdx.x * NPB_BIN;
    const int start = bin_base[blockIdx.x];
    const int end   = bin_base[blockIdx.x + 1];

    for (int idx = start + t; idx < end; idx += 256) {
        const int2 e = bins2[idx];
        const int n = e.x - nb;           // in [0, NPB_BIN) by construction
        int cur = e.y;
        #pragma unroll
        for (int j = 0; j < 4; ++j) {
            int old = atomicMin(&slot[4 * n + j], cur);
            if (old == EMPTY) break;
            cur = max(cur, old);
        }
    }
    __syncthreads();

    const int v = nb + t;
    if (t < NPB_BIN && v < N_NODES) {
        const int s0 = slot[4 * t + 0];
        const int s1 = slot[4 * t + 1];
        const int s2 = slot[4 * t + 2];
        const int s3 = slot[4 * t + 3];
        int4 r;
        r.x = (s0 < N_EDGES) ? src[s0] : -1;
        r.y = (s1 < N_EDGES) ? src[s1] : -1;
        r.z = (s2 < N_EDGES) ? src[s2] : -1;
        r.w = (s3 < N_EDGES) ? src[s3] : -1;
        srcs4[v] = r;
    }
}

// ---------------------------------------------------------------------------
// Fused sort-conv + BN statistics (bucketed atomics). Proven R4 structure.
// ---------------------------------------------------------------------------
__global__ __launch_bounds__(256)
void conv_stats_kernel(const float* __restrict__ x,
                       const int4* __restrict__ srcs4,    // per-node 4 gather rows
                       const float* __restrict__ bp,      // 128 floats (this layer)
                       const float* __restrict__ cw,
                       const float* __restrict__ cb,
                       const float* __restrict__ a,
                       float* __restrict__ h,
                       float* __restrict__ stats_part) {  // [NBUCKETS][256]
    const int t    = threadIdx.x;
    const int d4   = t & (DIM4 - 1);
    const int nsub = t >> 5;

    const float4* __restrict__ x4 = (const float4*)x;
    float4*       __restrict__ h4 = (float4*)h;

    const float aa = a[0];
    const float c0 = cw[0], c1 = cw[1], c2 = cw[2], c3 = cw[3];
    const float cbv = cb[0];
    const float4 bpv = ((const float4*)bp)[d4];

    const int v0 = blockIdx.x * NODES_PER_BLOCK + nsub;   // < N_NODES always
    const int v1 = v0 + NODES_PER_ITER;

    const int4 s0 = srcs4[v0];
    const int4 s1 = srcs4[v1];

    // unconditional gathers (clamped row), selects afterwards
    float4 g00 = x4[(size_t)max(s0.x, 0) * DIM4 + d4];
    float4 g01 = x4[(size_t)max(s0.y, 0) * DIM4 + d4];
    float4 g02 = x4[(size_t)max(s0.z, 0) * DIM4 + d4];
    float4 g03 = x4[(size_t)max(s0.w, 0) * DIM4 + d4];
    float4 g10 = x4[(size_t)max(s1.x, 0) * DIM4 + d4];
    float4 g11 = x4[(size_t)max(s1.y, 0) * DIM4 + d4];
    float4 g12 = x4[(size_t)max(s1.z, 0) * DIM4 + d4];
    float4 g13 = x4[(size_t)max(s1.w, 0) * DIM4 + d4];
    float4 xv0 = x4[(size_t)v0 * DIM4 + d4];
    float4 xv1 = x4[(size_t)v1 * DIM4 + d4];

    float4 s  = make_float4(0.f, 0.f, 0.f, 0.f);
    float4 s2 = make_float4(0.f, 0.f, 0.f, 0.f);

    #define CSWAP4(p, q) { float4 lo = f4min(p, q); float4 hi = f4max(p, q); p = lo; q = hi; }
    {
        float4 m0 = (s0.x >= 0) ? g00 : bpv;
        float4 m1 = (s0.y >= 0) ? g01 : bpv;
        float4 m2 = (s0.z >= 0) ? g02 : bpv;
        float4 m3 = (s0.w >= 0) ? g03 : bpv;
        CSWAP4(m0, m1); CSWAP4(m2, m3); CSWAP4(m0, m2); CSWAP4(m1, m3); CSWAP4(m1, m2);
        float4 hv = make_float4(cbv, cbv, cbv, cbv);
        hv = f4fma(c0, m0, hv);
        hv = f4fma(c1, m1, hv);
        hv = f4fma(c2, m2, hv);
        hv = f4fma(c3, m3, hv);
        hv = f4fma(aa, xv0, hv);
        h4[(size_t)v0 * DIM4 + d4] = hv;
        s  = f4add(s, hv);
        s2 = f4add(s2, make_float4(hv.x*hv.x, hv.y*hv.y, hv.z*hv.z, hv.w*hv.w));
    }
    {
        float4 m0 = (s1.x >= 0) ? g10 : bpv;
        float4 m1 = (s1.y >= 0) ? g11 : bpv;
        float4 m2 = (s1.z >= 0) ? g12 : bpv;
        float4 m3 = (s1.w >= 0) ? g13 : bpv;
        CSWAP4(m0, m1); CSWAP4(m2, m3); CSWAP4(m0, m2); CSWAP4(m1, m3); CSWAP4(m1, m2);
        float4 hv = make_float4(cbv, cbv, cbv, cbv);
        hv = f4fma(c0, m0, hv);
        hv = f4fma(c1, m1, hv);
        hv = f4fma(c2, m2, hv);
        hv = f4fma(c3, m3, hv);
        hv = f4fma(aa, xv1, hv);
        h4[(size_t)v1 * DIM4 + d4] = hv;
        s  = f4add(s, hv);
        s2 = f4add(s2, make_float4(hv.x*hv.x, hv.y*hv.y, hv.z*hv.z, hv.w*hv.w));
    }
    #undef CSWAP4

    // intra-wave: lane i += lane i+32 (same d4 column, different node)
    s.x  += __shfl_down(s.x, 32);  s.y  += __shfl_down(s.y, 32);
    s.z  += __shfl_down(s.z, 32);  s.w  += __shfl_down(s.w, 32);
    s2.x += __shfl_down(s2.x, 32); s2.y += __shfl_down(s2.y, 32);
    s2.z += __shfl_down(s2.z, 32); s2.w += __shfl_down(s2.w, 32);

    __shared__ float4 ls[4][32];
    __shared__ float4 ls2[4][32];
    const int wave = t >> 6;
    const int lane = t & 63;
    if (lane < 32) { ls[wave][lane] = s; ls2[wave][lane] = s2; }
    __syncthreads();
    if (t < 32) {
        float* bucket = stats_part + (size_t)(blockIdx.x & (NBUCKETS - 1)) * 256;
        float4 fs  = f4add(f4add(ls[0][t],  ls[1][t]),  f4add(ls[2][t],  ls[3][t]));
        float4 fs2 = f4add(f4add(ls2[0][t], ls2[1][t]), f4add(ls2[2][t], ls2[3][t]));
        atomicAdd(&bucket[4*t + 0], fs.x);
        atomicAdd(&bucket[4*t + 1], fs.y);
        atomicAdd(&bucket[4*t + 2], fs.z);
        atomicAdd(&bucket[4*t + 3], fs.w);
        atomicAdd(&bucket[DIM + 4*t + 0], fs2.x);
        atomicAdd(&bucket[DIM + 4*t + 1], fs2.y);
        atomicAdd(&bucket[DIM + 4*t + 2], fs2.z);
        atomicAdd(&bucket[DIM + 4*t + 3], fs2.w);
    }
}

// ---------------------------------------------------------------------------
// BN apply with inline bucket finalize: each block sums the 16 bucket
// partials itself (L2-hot), computes mu/invstd in LDS, applies BN+residual.
// ---------------------------------------------------------------------------
__global__ __launch_bounds__(256)
void bn_apply_kernel(const float* __restrict__ xin,
                     const float* __restrict__ h,
                     const float* __restrict__ stats_part,  // [NBUCKETS][256]
                     const float* __restrict__ g,
                     const float* __restrict__ be,
                     float* __restrict__ xout) {
    __shared__ float acc[256];
    const int t = threadIdx.x;

    float ssum = 0.f;
    #pragma unroll
    for (int k = 0; k < NBUCKETS; ++k) ssum += stats_part[k * 256 + t];
    acc[t] = ssum;
    __syncthreads();
    if (t < 128) {
        constexpr float invN = 1.0f / (float)N_NODES;
        float mu = acc[t] * invN;
        float iv = rsqrtf(acc[128 + t] * invN - mu * mu + BN_EPS);
        acc[t]       = mu;
        acc[128 + t] = iv;
    }
    __syncthreads();

    const int idx = blockIdx.x * 256 + t;   // float4 index; grid exact
    const int d4 = idx & (DIM4 - 1);

    const float4 mu4 = make_float4(acc[4*d4+0], acc[4*d4+1], acc[4*d4+2], acc[4*d4+3]);
    const float4 iv4 = make_float4(acc[128+4*d4+0], acc[128+4*d4+1],
                                   acc[128+4*d4+2], acc[128+4*d4+3]);
    const float4 hv = ((const float4*)h)[idx];
    const float4 xv = ((const float4*)xin)[idx];
    const float4 gv = ((const float4*)g)[d4];
    const float4 bv = ((const float4*)be)[d4];

    float4 o;
    o.x = xv.x + (hv.x - mu4.x) * iv4.x * gv.x + bv.x;
    o.y = xv.y + (hv.y - mu4.y) * iv4.y * gv.y + bv.y;
    o.z = xv.z + (hv.z - mu4.z) * iv4.z * gv.z + bv.z;
    o.w = xv.w + (hv.w - mu4.w) * iv4.w * gv.w + bv.w;
    ((float4*)xout)[idx] = o;
}

extern "C" void kernel_launch(void* const* d_in, const int* in_sizes, int n_in,
                              void* d_out, int out_size, void* d_ws, size_t ws_size,
                              hipStream_t stream) {
    const float* x0  = (const float*)d_in[0];
    const int*   ei  = (const int*)d_in[1];
    const int*   src = ei;               // edge_index[0]
    const int*   dst = ei + N_EDGES;     // edge_index[1]

    const float* W[2]; const float* b[2]; const float* cw[2]; const float* cb[2];
    const float* a[2]; const float* g[2]; const float* be[2]; const float* blank[2];
    for (int i = 0; i < 2; ++i) {
        int o = 2 + 8 * i;
        W[i]     = (const float*)d_in[o + 0];
        b[i]     = (const float*)d_in[o + 1];
        cw[i]    = (const float*)d_in[o + 2];
        cb[i]    = (const float*)d_in[o + 3];
        a[i]     = (const float*)d_in[o + 4];
        g[i]     = (const float*)d_in[o + 5];
        be[i]    = (const float*)d_in[o + 6];
        blank[i] = (const float*)d_in[o + 7];
    }

    // Workspace layout (re-poisoned 0xAA each call — everything used is
    // written before read): hist (P1), offsets/bin_base (P2), bins2 (P3),
    // srcs (P4), stats_part (zeroed in P1), bp (P4), h (conv).
    char* ws = (char*)d_ws;
    int*   srcs       = (int*)ws;                                 // 4N ints = 800 KB
    float* h          = (float*)(srcs + 4 * N_NODES);             // 25.6 MB
    int2*  bins2      = (int2*)(h + (size_t)N_NODES * DIM);       // 6.4 MB
    int*   hist       = (int*)(bins2 + N_EDGES);                  // 200*256 ints
    int*   offsets    = hist + P1_BLOCKS * NBINS;                 // 200*256 ints
    int*   bin_base   = offsets + P1_BLOCKS * NBINS;              // 257 ints
    float* stats_part = (float*)(bin_base + NBINS + 1);           // 2*16*256 floats
    float* bp         = stats_part + ZERO_WORDS;                  // 256 floats

    float* xout = (float*)d_out;

    // ---- partition-based single-pass selection ----
    part_count_kernel<<<P1_BLOCKS, 256, 0, stream>>>(dst, hist, stats_part);
    part_offsets_kernel<<<1, 256, 0, stream>>>(hist, offsets, bin_base);
    part_scatter_kernel<<<P1_BLOCKS, 256, 0, stream>>>(dst, offsets, bins2);
    select_kernel<<<NBINS + 2, 256, 0, stream>>>(
        bins2, bin_base, src, (int4*)srcs,
        W[0], b[0], blank[0], W[1], b[1], blank[1], bp);

    // ---- two layers: conv+stats, then BN apply w/ inline finalize ----
    for (int l = 0; l < 2; ++l) {
        const float* xin = (l == 0) ? x0 : xout;
        float* sp = stats_part + (size_t)l * NBUCKETS * 256;
        conv_stats_kernel<<<CONV_GRID, 256, 0, stream>>>(
            xin, (const int4*)srcs, bp + l * DIM, cw[l], cb[l], a[l], h, sp);
        bn_apply_kernel<<<(N_NODES * DIM4) / 256, 256, 0, stream>>>(
            xin, h, sp, g[l], be[l], xout);
    }
}

// Round 10
// 197.353 us; speedup vs baseline: 1.1173x; 1.0952x over previous
//
#include <hip/hip_runtime.h>
#include <hip/hip_fp16.h>
#include <cstring>

// Problem constants (fixed by reference setup_inputs)
constexpr int N_NODES = 50000;
constexpr int N_EDGES = 800000;
constexpr int DIM     = 128;
constexpr int DIM4    = DIM / 4;          // 32 float4 columns
constexpr float BN_EPS = 1e-5f;

constexpr int EMPTY = 0x7F7F7F7F;         // > any edge index; min-stable sentinel

// Two-stage select: 16 node chunks x 16 edge chunks, 1024-thread scan blocks.
constexpr int NC = 16;
constexpr int EC = 16;
constexpr int NODES_PER_NC = N_NODES / NC;      // 3125 (50 KB LDS table)
constexpr int EDGES_PER_EC = N_EDGES / EC;      // 50000
constexpr int E4_PER_EC    = EDGES_PER_EC / 4;  // 12500 int4 loads per chunk
constexpr int SEL_THREADS  = 1024;

constexpr int NBUCKETS = 16;              // stats buckets (cheap inline reduce)
constexpr int ZERO_WORDS = 2 * NBUCKETS * 256;   // 8192 = 8 stageA blocks x 1024

// Conv: proven R4 structure. 256 threads = 8 nodes x 32 f4-cols, 2 iters.
// Layer 0 additionally merges the 16 per-chunk top-4 lists inline (stageB
// eliminated) and emits srcs4 for layer 1.
constexpr int NODES_PER_ITER  = 8;
constexpr int NODES_PER_BLOCK = 16;
constexpr int CONV_GRID = N_NODES / NODES_PER_BLOCK;   // 3125 exact, no guard

// ---------------- helpers ----------------
__device__ inline float4 f4min(float4 a, float4 b) {
    return make_float4(fminf(a.x,b.x), fminf(a.y,b.y), fminf(a.z,b.z), fminf(a.w,b.w));
}
__device__ inline float4 f4max(float4 a, float4 b) {
    return make_float4(fmaxf(a.x,b.x), fmaxf(a.y,b.y), fmaxf(a.z,b.z), fmaxf(a.w,b.w));
}
__device__ inline float4 f4add(float4 a, float4 b) {
    return make_float4(a.x+b.x, a.y+b.y, a.z+b.z, a.w+b.w);
}
__device__ inline float4 f4fma(float s, float4 v, float4 acc) {   // acc + s*v
    return make_float4(fmaf(s,v.x,acc.x), fmaf(s,v.y,acc.y), fmaf(s,v.z,acc.z), fmaf(s,v.w,acc.w));
}
__device__ inline __half2 u2h2(unsigned u) { __half2 h; memcpy(&h, &u, 4); return h; }
__device__ inline unsigned h22u(__half2 h) { unsigned u; memcpy(&u, &h, 4); return u; }
__device__ inline float4 q2f4(uint2 q) {                 // fp16x4 -> fp32x4
    const float2 lo = __half22float2(u2h2(q.x));
    const float2 hi = __half22float2(u2h2(q.y));
    return make_float4(lo.x, lo.y, hi.x, hi.y);
}
__device__ inline uint2 f42q(float4 v) {                 // fp32x4 -> fp16x4
    uint2 u;
    u.x = h22u(__floats2half2_rn(v.x, v.y));
    u.y = h22u(__floats2half2_rn(v.z, v.w));
    return u;
}

// ---------------------------------------------------------------------------
// Select stage A: block (nc, ec) scans edge chunk ec with 1024 threads,
// inserts edges whose dst lies in node chunk nc into an LDS top-4 table
// (cascaded LDS atomicMin = concurrent sorted insert), then streams the
// table to tables[ec][node]. Housekeeping folded in: blocks 0-7 zero
// stats_part; blocks NC*EC / NC*EC+1 compute blank projections bp.
// ---------------------------------------------------------------------------
__global__ __launch_bounds__(SEL_THREADS)
void select_stageA_kernel(const int* __restrict__ dst,
                          int* __restrict__ tables,
                          float* __restrict__ stats_part,
                          const float* __restrict__ W0, const float* __restrict__ b0,
                          const float* __restrict__ bl0,
                          const float* __restrict__ W1, const float* __restrict__ b1,
                          const float* __restrict__ bl1,
                          float* __restrict__ bp) {
    const int t = threadIdx.x;

    if (blockIdx.x >= NC * EC) {          // blank-projection blocks
        if (t < DIM) {
            int l = blockIdx.x - NC * EC;
            const float* W  = l ? W1  : W0;
            const float* b  = l ? b1  : b0;
            const float* bl = l ? bl1 : bl0;
            float s = 0.f;
            #pragma unroll 8
            for (int j = 0; j < DIM; ++j) s += W[t * DIM + j] * bl[j];
            bp[l * DIM + t] = s + b[t];
        }
        return;
    }

    const int gid = blockIdx.x * SEL_THREADS + t;
    if (gid < ZERO_WORDS) stats_part[gid] = 0.f;    // blocks 0-7 zero stats

    __shared__ int slot[NODES_PER_NC * 4];    // 50 KB
    const int nc = blockIdx.x & (NC - 1);
    const int ec = blockIdx.x >> 4;

    for (int i = t; i < NODES_PER_NC * 4; i += SEL_THREADS) slot[i] = EMPTY;
    __syncthreads();

    const int r0 = nc * NODES_PER_NC;
    const int4* __restrict__ dst4 = (const int4*)dst;
    const int base4 = ec * E4_PER_EC;
    for (int i = t; i < E4_PER_EC; i += SEL_THREADS) {
        const int4 d = dst4[base4 + i];
        const int ebase = 4 * (base4 + i);
        #define TRY_INS(comp, off) {                                        \
            unsigned n_ = (unsigned)((comp) - r0);                          \
            if (n_ < (unsigned)NODES_PER_NC) {                              \
                int cur_ = ebase + (off);                                   \
                _Pragma("unroll")                                           \
                for (int j_ = 0; j_ < 4; ++j_) {                            \
                    int old_ = atomicMin(&slot[4 * n_ + j_], cur_);         \
                    if (old_ == EMPTY) break;                               \
                    cur_ = max(cur_, old_);                                 \
                } } }
        TRY_INS(d.x, 0); TRY_INS(d.y, 1); TRY_INS(d.z, 2); TRY_INS(d.w, 3);
        #undef TRY_INS
    }
    __syncthreads();

    int4* __restrict__ out = (int4*)tables + (size_t)ec * N_NODES + r0;
    const int4* __restrict__ sl4 = (const int4*)slot;
    for (int n = t; n < NODES_PER_NC; n += SEL_THREADS) out[n] = sl4[n];
}

// ---------------------------------------------------------------------------
// Fused sort-conv + BN statistics. do_merge=1 (layer 0): cooperatively load
// the block's 16-node x 16-chunk table tile (4 KB, one coalesced shot),
// merge branchlessly (bitonic half-cleaner), map through src, publish srcs4
// for layer 1 — stageB kernel eliminated. do_merge=0 (layer 1): read srcs4.
// h is stored fp16 (uint2/node-col): halves the h streaming traffic; BN
// statistics stay fp32 from registers.
// ---------------------------------------------------------------------------
__global__ __launch_bounds__(256)
void conv_stats_kernel(const float* __restrict__ x,
                       const int* __restrict__ tables,
                       const int* __restrict__ src,
                       int4* __restrict__ srcs4,
                       const float* __restrict__ bp,      // 128 floats (this layer)
                       const float* __restrict__ cw,
                       const float* __restrict__ cb,
                       const float* __restrict__ a,
                       uint2* __restrict__ h2,            // fp16 h out
                       float* __restrict__ stats_part,    // [NBUCKETS][256]
                       const int do_merge) {
    __shared__ int4 srcs_lds[NODES_PER_BLOCK];
    __shared__ int4 tile[EC][NODES_PER_BLOCK];

    const int t    = threadIdx.x;
    const int d4   = t & (DIM4 - 1);
    const int nsub = t >> 5;
    const int v0b  = blockIdx.x * NODES_PER_BLOCK;

    if (do_merge) {
        // one coalesced tile load: thread t -> chunk t>>4, node t&15
        tile[t >> 4][t & 15] =
            ((const int4*)tables)[(size_t)(t >> 4) * N_NODES + v0b + (t & 15)];
        __syncthreads();
        if (t < NODES_PER_BLOCK) {
            int4 c = tile[0][t];
            int a0 = c.x, a1 = c.y, a2 = c.z, a3 = c.w;
            #define MERGE4(cx, cy, cz, cw_) {                            \
                int m0 = min(a0, (cw_)), m1 = min(a1, (cz));             \
                int m2 = min(a2, (cy)), m3 = min(a3, (cx));              \
                int u_;                                                  \
                u_ = min(m0, m2); m2 = max(m0, m2); m0 = u_;             \
                u_ = min(m1, m3); m3 = max(m1, m3); m1 = u_;             \
                u_ = min(m0, m1); m1 = max(m0, m1); m0 = u_;             \
                u_ = min(m2, m3); m3 = max(m2, m3); m2 = u_;             \
                a0 = m0; a1 = m1; a2 = m2; a3 = m3; }
            #pragma unroll
            for (int ec = 1; ec < EC; ++ec) {
                c = tile[ec][t];
                MERGE4(c.x, c.y, c.z, c.w);
            }
            #undef MERGE4
            int4 r;
            r.x = (a0 < N_EDGES) ? src[a0] : -1;
            r.y = (a1 < N_EDGES) ? src[a1] : -1;
            r.z = (a2 < N_EDGES) ? src[a2] : -1;
            r.w = (a3 < N_EDGES) ? src[a3] : -1;
            srcs_lds[t] = r;
            srcs4[v0b + t] = r;               // publish for layer 1
        }
        __syncthreads();
    } else {
        if (t < NODES_PER_BLOCK) srcs_lds[t] = srcs4[v0b + t];
        __syncthreads();
    }

    const float4* __restrict__ x4 = (const float4*)x;

    const float aa = a[0];
    const float c0 = cw[0], c1 = cw[1], c2 = cw[2], c3 = cw[3];
    const float cbv = cb[0];
    const float4 bpv = ((const float4*)bp)[d4];

    const int v0 = v0b + nsub;
    const int v1 = v0 + NODES_PER_ITER;

    const int4 s0 = srcs_lds[nsub];
    const int4 s1 = srcs_lds[nsub + NODES_PER_ITER];

    // unconditional gathers (clamped row), selects afterwards
    float4 g00 = x4[(size_t)max(s0.x, 0) * DIM4 + d4];
    float4 g01 = x4[(size_t)max(s0.y, 0) * DIM4 + d4];
    float4 g02 = x4[(size_t)max(s0.z, 0) * DIM4 + d4];
    float4 g03 = x4[(size_t)max(s0.w, 0) * DIM4 + d4];
    float4 g10 = x4[(size_t)max(s1.x, 0) * DIM4 + d4];
    float4 g11 = x4[(size_t)max(s1.y, 0) * DIM4 + d4];
    float4 g12 = x4[(size_t)max(s1.z, 0) * DIM4 + d4];
    float4 g13 = x4[(size_t)max(s1.w, 0) * DIM4 + d4];
    float4 xv0 = x4[(size_t)v0 * DIM4 + d4];
    float4 xv1 = x4[(size_t)v1 * DIM4 + d4];

    float4 s  = make_float4(0.f, 0.f, 0.f, 0.f);
    float4 s2 = make_float4(0.f, 0.f, 0.f, 0.f);

    #define CSWAP4(p, q) { float4 lo = f4min(p, q); float4 hi = f4max(p, q); p = lo; q = hi; }
    {
        float4 m0 = (s0.x >= 0) ? g00 : bpv;
        float4 m1 = (s0.y >= 0) ? g01 : bpv;
        float4 m2 = (s0.z >= 0) ? g02 : bpv;
        float4 m3 = (s0.w >= 0) ? g03 : bpv;
        CSWAP4(m0, m1); CSWAP4(m2, m3); CSWAP4(m0, m2); CSWAP4(m1, m3); CSWAP4(m1, m2);
        float4 hv = make_float4(cbv, cbv, cbv, cbv);
        hv = f4fma(c0, m0, hv);
        hv = f4fma(c1, m1, hv);
        hv = f4fma(c2, m2, hv);
        hv = f4fma(c3, m3, hv);
        hv = f4fma(aa, xv0, hv);
        h2[(size_t)v0 * DIM4 + d4] = f42q(hv);
        s  = f4add(s, hv);
        s2 = f4add(s2, make_float4(hv.x*hv.x, hv.y*hv.y, hv.z*hv.z, hv.w*hv.w));
    }
    {
        float4 m0 = (s1.x >= 0) ? g10 : bpv;
        float4 m1 = (s1.y >= 0) ? g11 : bpv;
        float4 m2 = (s1.z >= 0) ? g12 : bpv;
        float4 m3 = (s1.w >= 0) ? g13 : bpv;
        CSWAP4(m0, m1); CSWAP4(m2, m3); CSWAP4(m0, m2); CSWAP4(m1, m3); CSWAP4(m1, m2);
        float4 hv = make_float4(cbv, cbv, cbv, cbv);
        hv = f4fma(c0, m0, hv);
        hv = f4fma(c1, m1, hv);
        hv = f4fma(c2, m2, hv);
        hv = f4fma(c3, m3, hv);
        hv = f4fma(aa, xv1, hv);
        h2[(size_t)v1 * DIM4 + d4] = f42q(hv);
        s  = f4add(s, hv);
        s2 = f4add(s2, make_float4(hv.x*hv.x, hv.y*hv.y, hv.z*hv.z, hv.w*hv.w));
    }
    #undef CSWAP4

    // intra-wave: lane i += lane i+32 (same d4 column, different node)
    s.x  += __shfl_down(s.x, 32);  s.y  += __shfl_down(s.y, 32);
    s.z  += __shfl_down(s.z, 32);  s.w  += __shfl_down(s.w, 32);
    s2.x += __shfl_down(s2.x, 32); s2.y += __shfl_down(s2.y, 32);
    s2.z += __shfl_down(s2.z, 32); s2.w += __shfl_down(s2.w, 32);

    __shared__ float4 ls[4][32];
    __shared__ float4 ls2[4][32];
    const int wave = t >> 6;
    const int lane = t & 63;
    if (lane < 32) { ls[wave][lane] = s; ls2[wave][lane] = s2; }
    __syncthreads();
    if (t < 32) {
        float* bucket = stats_part + (size_t)(blockIdx.x & (NBUCKETS - 1)) * 256;
        float4 fs  = f4add(f4add(ls[0][t],  ls[1][t]),  f4add(ls[2][t],  ls[3][t]));
        float4 fs2 = f4add(f4add(ls2[0][t], ls2[1][t]), f4add(ls2[2][t], ls2[3][t]));
        atomicAdd(&bucket[4*t + 0], fs.x);
        atomicAdd(&bucket[4*t + 1], fs.y);
        atomicAdd(&bucket[4*t + 2], fs.z);
        atomicAdd(&bucket[4*t + 3], fs.w);
        atomicAdd(&bucket[DIM + 4*t + 0], fs2.x);
        atomicAdd(&bucket[DIM + 4*t + 1], fs2.y);
        atomicAdd(&bucket[DIM + 4*t + 2], fs2.z);
        atomicAdd(&bucket[DIM + 4*t + 3], fs2.w);
    }
}

// ---------------------------------------------------------------------------
// BN apply with inline bucket finalize: each block sums the 16 bucket
// partials itself (L2-hot), computes mu/invstd in LDS, applies BN+residual.
// h read as fp16 (halved streaming traffic).
// ---------------------------------------------------------------------------
__global__ __launch_bounds__(256)
void bn_apply_kernel(const float* __restrict__ xin,
                     const uint2* __restrict__ h2,
                     const float* __restrict__ stats_part,  // [NBUCKETS][256]
                     const float* __restrict__ g,
                     const float* __restrict__ be,
                     float* __restrict__ xout) {
    __shared__ float acc[256];
    const int t = threadIdx.x;

    float ssum = 0.f;
    #pragma unroll
    for (int k = 0; k < NBUCKETS; ++k) ssum += stats_part[k * 256 + t];
    acc[t] = ssum;
    __syncthreads();
    if (t < 128) {
        constexpr float invN = 1.0f / (float)N_NODES;
        float mu = acc[t] * invN;
        float iv = rsqrtf(acc[128 + t] * invN - mu * mu + BN_EPS);
        acc[t]       = mu;
        acc[128 + t] = iv;
    }
    __syncthreads();

    const int idx = blockIdx.x * 256 + t;   // float4 index; grid exact
    const int d4 = idx & (DIM4 - 1);

    const float4 mu4 = make_float4(acc[4*d4+0], acc[4*d4+1], acc[4*d4+2], acc[4*d4+3]);
    const float4 iv4 = make_float4(acc[128+4*d4+0], acc[128+4*d4+1],
                                   acc[128+4*d4+2], acc[128+4*d4+3]);
    const float4 hv = q2f4(h2[idx]);
    const float4 xv = ((const float4*)xin)[idx];
    const float4 gv = ((const float4*)g)[d4];
    const float4 bv = ((const float4*)be)[d4];

    float4 o;
    o.x = xv.x + (hv.x - mu4.x) * iv4.x * gv.x + bv.x;
    o.y = xv.y + (hv.y - mu4.y) * iv4.y * gv.y + bv.y;
    o.z = xv.z + (hv.z - mu4.z) * iv4.z * gv.z + bv.z;
    o.w = xv.w + (hv.w - mu4.w) * iv4.w * gv.w + bv.w;
    ((float4*)xout)[idx] = o;
}

extern "C" void kernel_launch(void* const* d_in, const int* in_sizes, int n_in,
                              void* d_out, int out_size, void* d_ws, size_t ws_size,
                              hipStream_t stream) {
    const float* x0  = (const float*)d_in[0];
    const int*   ei  = (const int*)d_in[1];
    const int*   src = ei;               // edge_index[0]
    const int*   dst = ei + N_EDGES;     // edge_index[1]

    const float* W[2]; const float* b[2]; const float* cw[2]; const float* cb[2];
    const float* a[2]; const float* g[2]; const float* be[2]; const float* blank[2];
    for (int i = 0; i < 2; ++i) {
        int o = 2 + 8 * i;
        W[i]     = (const float*)d_in[o + 0];
        b[i]     = (const float*)d_in[o + 1];
        cw[i]    = (const float*)d_in[o + 2];
        cb[i]    = (const float*)d_in[o + 3];
        a[i]     = (const float*)d_in[o + 4];
        g[i]     = (const float*)d_in[o + 5];
        be[i]    = (const float*)d_in[o + 6];
        blank[i] = (const float*)d_in[o + 7];
    }

    // Workspace layout (re-poisoned 0xAA each call — everything used is
    // written before read). No aliasing: conv0 reads tables while writing
    // h2 and srcs4.
    char* ws = (char*)d_ws;
    int*   srcs       = (int*)ws;                                 // 4N ints = 0.8 MB
    int*   tables     = srcs + 4 * N_NODES;                       // 16*4N ints = 12.8 MB
    uint2* h2         = (uint2*)(tables + (size_t)EC * 4 * N_NODES); // 12.8 MB fp16 h
    float* stats_part = (float*)(h2 + (size_t)N_NODES * DIM4);    // 2*16*256 floats
    float* bp         = stats_part + ZERO_WORDS;                  // 256 floats

    float* xout = (float*)d_out;

    // ---- selection stage A (+ stats zero + blank projections) ----
    select_stageA_kernel<<<NC * EC + 2, SEL_THREADS, 0, stream>>>(
        dst, tables, stats_part,
        W[0], b[0], blank[0], W[1], b[1], blank[1], bp);

    // ---- two layers: conv+stats (l0 merges inline), BN apply ----
    for (int l = 0; l < 2; ++l) {
        const float* xin = (l == 0) ? x0 : xout;
        float* sp = stats_part + (size_t)l * NBUCKETS * 256;
        conv_stats_kernel<<<CONV_GRID, 256, 0, stream>>>(
            xin, tables, src, (int4*)srcs, bp + l * DIM,
            cw[l], cb[l], a[l], h2, sp, (l == 0) ? 1 : 0);
        bn_apply_kernel<<<(N_NODES * DIM4) / 256, 256, 0, stream>>>(
            xin, h2, sp, g[l], be[l], xout);
    }
}